// Round 4
// baseline (30.661 us; speedup 1.0000x reference)
//
#include <hip/hip_runtime.h>

// LocallyConnected2d: out[b,o,l] = sum_d patches[b,d,l] * w[d,l,o] + bias[o,l]
// B=8, DEPTH=288, L=2304, C_OUT=32, fp32. Weight = 85 MB read once (L3-resident
// across replays) -> on-chip latency-bound. R4: maximize bytes in flight:
//  (a) LDS 53->37 KB (alias red into patches) => 4 blocks/CU (4 waves/SIMD)
//  (b) depth-3 rotating weight prefetch (wA/wB/wC) => 8-12 KB outstanding/wave

constexpr int NB    = 8;
constexpr int CIN   = 32;
constexpr int HWD   = 48;
constexpr int COUT  = 32;
constexpr int DEPTH = 288;
constexpr int LTOT  = 2304;
constexpr int LB    = 4;                  // locations per block
constexpr int NBLK  = LTOT / LB;          // 576
constexpr int PL    = DEPTH * NB + 8;     // 2312: padded per-l stride (words)
constexpr int WSTR  = LTOT * COUT;        // 73728 floats between d-planes

#define FMAS(P0, P1, WV)                                                        \
    acc[0].x = fmaf((P0).x, (WV).x, acc[0].x); acc[0].y = fmaf((P0).x, (WV).y, acc[0].y); \
    acc[0].z = fmaf((P0).x, (WV).z, acc[0].z); acc[0].w = fmaf((P0).x, (WV).w, acc[0].w); \
    acc[1].x = fmaf((P0).y, (WV).x, acc[1].x); acc[1].y = fmaf((P0).y, (WV).y, acc[1].y); \
    acc[1].z = fmaf((P0).y, (WV).z, acc[1].z); acc[1].w = fmaf((P0).y, (WV).w, acc[1].w); \
    acc[2].x = fmaf((P0).z, (WV).x, acc[2].x); acc[2].y = fmaf((P0).z, (WV).y, acc[2].y); \
    acc[2].z = fmaf((P0).z, (WV).z, acc[2].z); acc[2].w = fmaf((P0).z, (WV).w, acc[2].w); \
    acc[3].x = fmaf((P0).w, (WV).x, acc[3].x); acc[3].y = fmaf((P0).w, (WV).y, acc[3].y); \
    acc[3].z = fmaf((P0).w, (WV).z, acc[3].z); acc[3].w = fmaf((P0).w, (WV).w, acc[3].w); \
    acc[4].x = fmaf((P1).x, (WV).x, acc[4].x); acc[4].y = fmaf((P1).x, (WV).y, acc[4].y); \
    acc[4].z = fmaf((P1).x, (WV).z, acc[4].z); acc[4].w = fmaf((P1).x, (WV).w, acc[4].w); \
    acc[5].x = fmaf((P1).y, (WV).x, acc[5].x); acc[5].y = fmaf((P1).y, (WV).y, acc[5].y); \
    acc[5].z = fmaf((P1).y, (WV).z, acc[5].z); acc[5].w = fmaf((P1).y, (WV).w, acc[5].w); \
    acc[6].x = fmaf((P1).z, (WV).x, acc[6].x); acc[6].y = fmaf((P1).z, (WV).y, acc[6].y); \
    acc[6].z = fmaf((P1).z, (WV).z, acc[6].z); acc[6].w = fmaf((P1).z, (WV).w, acc[6].w); \
    acc[7].x = fmaf((P1).w, (WV).x, acc[7].x); acc[7].y = fmaf((P1).w, (WV).y, acc[7].y); \
    acc[7].z = fmaf((P1).w, (WV).z, acc[7].z); acc[7].w = fmaf((P1).w, (WV).w, acc[7].w);

#define PRELOAD(W, CH)                                                          \
    { _Pragma("unroll") for (int j = 0; j < 4; ++j)                             \
        W[j] = *reinterpret_cast<const float4*>(wp + (size_t)((CH) * 4 + j) * WSTR); }

#define COMPUTE(W, CH)                                                          \
    { _Pragma("unroll") for (int j = 0; j < 4; ++j) {                           \
        const int i = (CH) * 4 + j;                                             \
        const float4 p0 = *reinterpret_cast<const float4*>(pbase + i * NB);     \
        const float4 p1 = *reinterpret_cast<const float4*>(pbase + i * NB + 4); \
        FMAS(p0, p1, W[j]); } }

__global__ __launch_bounds__(256, 4) void lc2d(const float* __restrict__ x,
                                               const float* __restrict__ wgt,
                                               const float* __restrict__ bias,
                                               float* __restrict__ out) {
    __shared__ float lds[LB * PL];     // 36,992 B; red (16 KB) aliases this after main loop
    float* const patches = lds;
    float* const red     = lds;        // [wave][b][lsub][o], 4096 floats

    const int tid = threadIdx.x;
    // XCD-chunked bijective swizzle (576 % 8 == 0)
    const int bid   = blockIdx.x;
    const int ltile = (bid & 7) * (NBLK / 8) + (bid >> 3);
    const int l0    = ltile * LB;
    const int h0    = l0 / HWD;
    const int w0    = l0 - h0 * HWD;   // 48 % 4 == 0: all 4 l's in one row

    // ---- stage patches[ls][d][b]: 9216 elems, 36/thread ----
    #pragma unroll
    for (int k = 0; k < (LB * DEPTH * NB) / 256; ++k) {
        const int sidx = k * 256 + tid;
        const int b  = sidx & 7;
        const int t2 = sidx >> 3;
        const int d  = t2 % DEPTH;
        const int ls = t2 / DEPTH;
        const int c  = d / 9;          // torch unfold order d = c*9 + kh*3 + kw
        const int r9 = d - c * 9;
        const int kh = r9 / 3;
        const int kw = r9 - kh * 3;
        const int ih = h0 + kh - 1;
        const int iw = w0 + ls + kw - 1;
        float v = 0.f;
        if ((unsigned)ih < (unsigned)HWD && (unsigned)iw < (unsigned)HWD)
            v = x[((b * CIN + c) * HWD + ih) * HWD + iw];
        patches[ls * PL + d * NB + b] = v;
    }
    __syncthreads();

    // ---- main: wave owns 72 d's; lane = (dpar, lsub, og) ----
    const int wave = tid >> 6;
    const int lane = tid & 63;
    const int og   = lane & 7;         // o = og*4 .. og*4+3
    const int lsub = (lane >> 3) & 3;  // l = l0 + lsub
    const int dpar = lane >> 5;        // d half: +0 / +36
    const int d0   = wave * 72 + dpar * 36;

    const float* wp    = wgt + (size_t)d0 * WSTR + (size_t)(l0 + lsub) * COUT + og * 4;
    const float* pbase = &patches[lsub * PL + d0 * NB];

    float4 acc[NB];
    #pragma unroll
    for (int b = 0; b < NB; ++b) acc[b] = make_float4(0.f, 0.f, 0.f, 0.f);

    // 36 d-steps = 9 chunks of 4; rotating 3-deep prefetch, vmcnt never drains
    float4 wA[4], wB[4], wC[4];
    PRELOAD(wA, 0) PRELOAD(wB, 1) PRELOAD(wC, 2)
    #pragma unroll
    for (int ch = 0; ch < 6; ch += 3) {
        COMPUTE(wA, ch)     PRELOAD(wA, ch + 3)
        COMPUTE(wB, ch + 1) PRELOAD(wB, ch + 4)
        COMPUTE(wC, ch + 2) PRELOAD(wC, ch + 5)
    }
    COMPUTE(wA, 6) COMPUTE(wB, 7) COMPUTE(wC, 8)

    // ---- reduce dpar halves, stash in red (aliases patches => barrier first) ----
    #pragma unroll
    for (int b = 0; b < NB; ++b) {
        acc[b].x += __shfl_xor(acc[b].x, 32);
        acc[b].y += __shfl_xor(acc[b].y, 32);
        acc[b].z += __shfl_xor(acc[b].z, 32);
        acc[b].w += __shfl_xor(acc[b].w, 32);
    }
    __syncthreads();                   // all waves done reading patches
    if (lane < 32) {
        #pragma unroll
        for (int b = 0; b < NB; ++b)
            *reinterpret_cast<float4*>(&red[(((wave * NB) + b) * LB + lsub) * COUT + og * 4]) = acc[b];
    }
    __syncthreads();

    // ---- combine 4 waves + bias; thread=(b,o) writes float4 over l ----
    const int ob = tid >> 5;
    const int oo = tid & 31;
    float s[LB];
    #pragma unroll
    for (int l = 0; l < LB; ++l)
        s[l] = red[((0 * NB + ob) * LB + l) * COUT + oo]
             + red[((1 * NB + ob) * LB + l) * COUT + oo]
             + red[((2 * NB + ob) * LB + l) * COUT + oo]
             + red[((3 * NB + ob) * LB + l) * COUT + oo];
    const float4 bv = *reinterpret_cast<const float4*>(bias + (size_t)oo * LTOT + l0);
    const float4 o4 = make_float4(s[0] + bv.x, s[1] + bv.y, s[2] + bv.z, s[3] + bv.w);
    *reinterpret_cast<float4*>(out + ((size_t)(ob * COUT + oo)) * LTOT + l0) = o4;
}

extern "C" void kernel_launch(void* const* d_in, const int* in_sizes, int n_in,
                              void* d_out, int out_size, void* d_ws, size_t ws_size,
                              hipStream_t stream) {
    const float* x    = (const float*)d_in[0];
    const float* wgt  = (const float*)d_in[1];
    const float* bias = (const float*)d_in[2];
    float* out        = (float*)d_out;
    lc2d<<<NBLK, 256, 0, stream>>>(x, wgt, bias, out);
}